// Round 14
// baseline (167.771 us; speedup 1.0000x reference)
//
#include <hip/hip_runtime.h>
#include <hip/hip_bf16.h>

// LightningAttention MI355X — round 22.
// R21 post-mortem: atomic-merge halved WRITE_SIZE exactly as predicted (25088->20736KB)
//   but bought only ~1us -> atomic drain ~solved; retire that line.
// Budget: fill 42.6 | qkv ~52 | k_zout ~45 (by subtraction; roofline ~10) | prep ~4.
// R22 target = k_zout occupancy: 74.2KB LDS capped it at 2 blocks/CU with 3
//   barrier-serialized phases (exposed serial A-frag prologue since R18 shrank its
//   staging shadow to 8KB). COLUMN-SPLIT: each block does 128 rows x 64 cols;
//   M halves to 32KB, boS dropped (bo via L2) -> LDS = 40960B EXACTLY -> 4 blocks/CU;
//   grid 1024 = 4 x 256 CUs = one balanced round. Cost: A-frag prologue + qws read
//   duplicated x2 (qws L2/L3-hot). Per-element arithmetic order unchanged -> absmax
//   must stay bit-identical 2.441e-4.
// k_prep / k_qkv identical to R21. 3 dispatches.
// B=8 T=8192 DM=128 H=8 Dh=16. Split-bf16 (hi+lo) on all MFMA surfaces except q' (bf16).

typedef __attribute__((ext_vector_type(8))) short short8;   // 8 bf16 (MFMA A/B frag)
typedef __attribute__((ext_vector_type(4))) float floatx4;  // MFMA C/D frag

#define DEV __device__ __forceinline__
#define MFMA __builtin_amdgcn_mfma_f32_16x16x32_bf16

#define XPAD 136   // x-tile row stride in shorts (17x16B slots)

DEV unsigned short bfh(float f) {
  unsigned int x = __float_as_uint(f);
  x += 0x7fffu + ((x >> 16) & 1u);     // RNE
  return (unsigned short)(x >> 16);
}
DEV float bfdec(unsigned short u) { return __uint_as_float(((unsigned int)u) << 16); }
DEV void splitf(float f, unsigned short& h, unsigned short& l) {
  h = bfh(f);
  l = bfh(f - bfdec(h));
}
DEV void split8(const float* p, short8& h8, short8& l8) {
  float4 a = *(const float4*)p;
  float4 b = *(const float4*)(p + 4);
  float v[8] = {a.x, a.y, a.z, a.w, b.x, b.y, b.z, b.w};
  union { short8 s; unsigned short u[8]; } H, L;
#pragma unroll
  for (int i = 0; i < 8; ++i) splitf(v[i], H.u[i], L.u[i]);
  h8 = H.s; l8 = L.s;
}

// Register transpose (verified R5-R7): C-layout tile val(n=lane16, m=mt*16+quad*4+r),
// rows m0/m1 -> split frag F[lane16][k=quad*8+j] over the 32-wide m-window.
DEV void xpose_frag(floatx4 m0, floatx4 m1, int lane16, int quad,
                    short8& hi, short8& lo) {
  union { short8 s; unsigned short u[8]; } H, L;
#pragma unroll
  for (int j = 0; j < 8; ++j) {
    int srcLane = lane16 + (((quad & 1) * 2 + (j >> 2)) << 4);
    float vA = __shfl(m0[j & 3], srcLane, 64);
    float vB = __shfl(m1[j & 3], srcLane, 64);
    float v = (quad < 2) ? vA : vB;
    splitf(v, H.u[j], L.u[j]);
  }
  hi = H.s; lo = L.s;
}

// async 16B global->LDS (per-lane gsrc; LDS dest must be wave-uniform base + lane*16)
DEV void async16(const void* g, void* l) {
  __builtin_amdgcn_global_load_lds(
      (const __attribute__((address_space(1))) unsigned int*)g,
      (__attribute__((address_space(3))) unsigned int*)l, 16, 0, 0);
}

// One 64-row GEMM tile: acc[mat][mt] = x_tile @ {Wq,Wk,Wv} (split-bf16, 48 MFMAs)
DEV void gemm_tile(const unsigned short* __restrict__ xh, const unsigned short* __restrict__ xl,
                   const unsigned short* __restrict__ WTh, const unsigned short* __restrict__ WTl,
                   const size_t* wbase, int lane16, int quad, floatx4 (&acc)[3][4]) {
#pragma unroll
  for (int i = 0; i < 3; ++i)
#pragma unroll
    for (int j = 0; j < 4; ++j) acc[i][j] = (floatx4){0.f, 0.f, 0.f, 0.f};

  short8 wh[2][3], wl[2][3];       // double-buffered weight frags
#pragma unroll
  for (int mat = 0; mat < 3; ++mat) {
    wh[0][mat] = *(const short8*)(WTh + wbase[mat]);
    wl[0][mat] = *(const short8*)(WTl + wbase[mat]);
  }
#pragma unroll
  for (int ks = 0; ks < 4; ++ks) {
    const int cur = ks & 1, nxt = cur ^ 1;
    if (ks < 3) {
#pragma unroll
      for (int mat = 0; mat < 3; ++mat) {
        wh[nxt][mat] = *(const short8*)(WTh + wbase[mat] + (ks + 1) * 32);
        wl[nxt][mat] = *(const short8*)(WTl + wbase[mat] + (ks + 1) * 32);
      }
    }
    short8 afh[4], afl[4];
#pragma unroll
    for (int mt = 0; mt < 4; ++mt) {
      int off = (mt * 16 + lane16) * XPAD + ks * 32 + quad * 8;
      afh[mt] = *(const short8*)&xh[off];
      afl[mt] = *(const short8*)&xl[off];
    }
#pragma unroll
    for (int mat = 0; mat < 3; ++mat) {
#pragma unroll
      for (int mt = 0; mt < 4; ++mt) {
        acc[mat][mt] = MFMA(afh[mt], wh[cur][mat], acc[mat][mt], 0, 0, 0);
        acc[mat][mt] = MFMA(afl[mt], wh[cur][mat], acc[mat][mt], 0, 0, 0);
        acc[mat][mt] = MFMA(afh[mt], wl[cur][mat], acc[mat][mt], 0, 0, 0);
      }
    }
  }
}

// Epilogue for one tile. Accumulates ksum into s_acc and ctx into c_acc (MFMA C-op);
// FINAL=true issues the single per-block set of atomics (early, so the drain overlaps
// the q-side work that follows).
template <bool FINAL>
DEV void epilogue_tile(floatx4 (&acc)[3][4], const float (*rc)[9], const float (*rs)[9],
                       int roff, int trow0, int b, int w, int lane16, int quad, int l,
                       const float* bq, const float* bk, const float* bv,
                       float* __restrict__ ctx, float* __restrict__ ksum,
                       unsigned short* __restrict__ qws,
                       float& s_acc, floatx4& c_acc) {
  {  // bias
    int col = w * 16 + lane16;
    float bias[3] = {bq[col], bk[col], bv[col]};
#pragma unroll
    for (int mat = 0; mat < 3; ++mat)
#pragma unroll
      for (int mt = 0; mt < 4; ++mt)
#pragma unroll
        for (int r = 0; r < 4; ++r) acc[mat][mt][r] += bias[mat];
  }
  const int d = lane16, jj = d & 7;

  // rope + elu+1 on K first (feeds ksum/ctx)
#pragma unroll
  for (int mt = 0; mt < 4; ++mt) {
#pragma unroll
    for (int r = 0; r < 4; ++r) {
      int tl = roff + mt * 16 + quad * 4 + r;
      float cc = rc[tl][jj], ss = rs[tl][jj];
      float v = acc[1][mt][r];
      float p = __shfl_xor(v, 8);          // pair (d, d+8)
      float nv = (d < 8) ? (v * cc - p * ss) : (p * ss + v * cc);
      acc[1][mt][r] = (nv > 0.f) ? (nv + 1.f) : __expf(nv);
    }
  }
  // ksum raw per-lane accumulation (reduce + atomic only on FINAL)
#pragma unroll
  for (int mt = 0; mt < 4; ++mt)
#pragma unroll
    for (int r = 0; r < 4; ++r) s_acc += acc[1][mt][r];
  if (FINAL) {
    float s = s_acc;
    s += __shfl_xor(s, 16);
    s += __shfl_xor(s, 32);
    if (l < 16) atomicAdd(&ksum[(b * 8 + w) * 16 + lane16], s);
  }
  // ctx accumulation via MFMA C-operand (atomics only on FINAL)
#pragma unroll
  for (int ks2 = 0; ks2 < 2; ++ks2) {
    short8 kh, kl, vh, vl;
    xpose_frag(acc[1][ks2 * 2], acc[1][ks2 * 2 + 1], lane16, quad, kh, kl);
    xpose_frag(acc[2][ks2 * 2], acc[2][ks2 * 2 + 1], lane16, quad, vh, vl);
    c_acc = MFMA(kh, vh, c_acc, 0, 0, 0);
    c_acc = MFMA(kl, vh, c_acc, 0, 0, 0);
    c_acc = MFMA(kh, vl, c_acc, 0, 0, 0);
  }
  if (FINAL) {
#pragma unroll
    for (int r = 0; r < 4; ++r)
      atomicAdd(&ctx[((size_t)(b * 8 + w) * 16 + quad * 4 + r) * 16 + lane16], c_acc[r]);
  }
  // rope + elu+1 on Q + q' stores (atomic drain overlaps this on FINAL; on tile 0 it
  // drains under tile 1's GEMM)
#pragma unroll
  for (int mt = 0; mt < 4; ++mt) {
#pragma unroll
    for (int r = 0; r < 4; ++r) {
      int tl = roff + mt * 16 + quad * 4 + r;
      float cc = rc[tl][jj], ss = rs[tl][jj];
      float v = acc[0][mt][r];
      float p = __shfl_xor(v, 8);          // pair (d, d+8)
      float nv = (d < 8) ? (v * cc - p * ss) : (p * ss + v * cc);
      acc[0][mt][r] = (nv > 0.f) ? (nv + 1.f) : __expf(nv);
    }
  }
#pragma unroll
  for (int mt = 0; mt < 4; ++mt)
#pragma unroll
    for (int r = 0; r < 4; ++r)
      qws[(size_t)(trow0 + mt * 16 + quad * 4 + r) * 128 + w * 16 + lane16] =
          bfh(acc[0][mt][r]);
}

// ---------------- k_prep: Wq/Wk/Wv split-transpose + zero ctx/ksum + rope table ----------------
__global__ void k_prep(const float* __restrict__ Wq, const float* __restrict__ Wk,
                       const float* __restrict__ Wv,
                       unsigned short* __restrict__ WTh, unsigned short* __restrict__ WTl,
                       float* __restrict__ ctxz,
                       float* __restrict__ RC, float* __restrict__ RS) {
  int gid = blockIdx.x * 256 + threadIdx.x;
  if (gid < 6144) {               // 3 mats x 128 n x 16 k-groups of 8
    int mat = gid >> 11, r = gid & 2047, n = r >> 4, k0 = (r & 15) * 8;
    const float* W = (mat == 0) ? Wq : (mat == 1) ? Wk : Wv;
    union { uint4 q; unsigned short u[8]; } oh, ol;
#pragma unroll
    for (int i = 0; i < 8; ++i) splitf(W[(size_t)(k0 + i) * 128 + n], oh.u[i], ol.u[i]);
    *(uint4*)&WTh[mat * 16384 + n * 128 + k0] = oh.q;
    *(uint4*)&WTl[mat * 16384 + n * 128 + k0] = ol.q;
  } else if (gid < 6144 + 17408) {
    ctxz[gid - 6144] = 0.0f;      // ctx (16384) + ksum (1024)
  } else if (gid < 23552 + 65536) {
    int idx = gid - 23552;        // t*8 + j, T=8192
    int t = idx >> 3, j = idx & 7;
    float invf = 1.0f / powf(10000.0f, (float)j * 0.125f);
    float s, c;
    sincosf((float)t * invf, &s, &c);
    RC[idx] = c; RS[idx] = s;     // bit-identical to the old per-block computation
  }
}

// ---------------- kernel 1: qkv, 2-tile pipelined, merged atomics. 512 blocks x 512 thr ----------------
__global__ __launch_bounds__(512) void k_qkv(
    const float* __restrict__ x,
    const unsigned short* __restrict__ WTh, const unsigned short* __restrict__ WTl,
    const float* __restrict__ bq, const float* __restrict__ bk, const float* __restrict__ bv,
    const float* __restrict__ RC, const float* __restrict__ RS,
    float* __restrict__ ctx, float* __restrict__ ksum,
    unsigned short* __restrict__ qws) {
  __shared__ unsigned short xh[2][64 * XPAD], xl[2][64 * XPAD];  // 69632B dbuf
  __shared__ float rc[128][9], rs[128][9];                        // 9216B
  const int tid = threadIdx.x;
  const int row0 = blockIdx.x * 128;
  const int b = row0 >> 13;     // 128 | 8192 -> constant across both tiles
  const int t0 = row0 & 8191;

  {  // rope table for all 128 rows: 512 threads x 2
#pragma unroll
    for (int it = 0; it < 2; ++it) {
      int ii = it * 512 + tid;
      int r = ii >> 3, j = ii & 7;
      int idx = (t0 + r) * 8 + j;
      rc[r][j] = RC[idx];
      rs[r][j] = RS[idx];
    }
  }
  {  // stage tile 0
    int r = tid >> 3, cg = (tid & 7) * 16;
    const float* xp = x + (size_t)(row0 + r) * 128 + cg;
    short8 h0, l0, h1, l1;
    split8(xp, h0, l0);
    split8(xp + 8, h1, l1);
    *(short8*)&xh[0][r * XPAD + cg] = h0;
    *(short8*)&xh[0][r * XPAD + cg + 8] = h1;
    *(short8*)&xl[0][r * XPAD + cg] = l0;
    *(short8*)&xl[0][r * XPAD + cg + 8] = l1;
  }
  __syncthreads();

  const int l = tid & 63, w = tid >> 6;       // wave w owns head w
  const int lane16 = l & 15, quad = l >> 4;

  size_t wbase[3];
#pragma unroll
  for (int mat = 0; mat < 3; ++mat)
    wbase[mat] = (size_t)mat * 16384 + (size_t)(w * 16 + lane16) * 128 + quad * 8;

  floatx4 acc[3][4];               // 48 AGPRs
  float s_acc = 0.f;               // ksum carry across tiles
  floatx4 c_acc = (floatx4){0.f, 0.f, 0.f, 0.f};  // ctx carry across tiles

  // ---- tile 0 GEMM ----
  gemm_tile(xh[0], xl[0], WTh, WTl, wbase, lane16, quad, acc);

  // ---- stage tile 1 (overlaps other block; split+write hidden by epi0 below) ----
  {
    int r = tid >> 3, cg = (tid & 7) * 16;
    const float* xp = x + (size_t)(row0 + 64 + r) * 128 + cg;
    short8 h0, l0, h1, l1;
    split8(xp, h0, l0);
    split8(xp + 8, h1, l1);
    *(short8*)&xh[1][r * XPAD + cg] = h0;
    *(short8*)&xh[1][r * XPAD + cg + 8] = h1;
    *(short8*)&xl[1][r * XPAD + cg] = l0;
    *(short8*)&xl[1][r * XPAD + cg + 8] = l1;
  }
  __syncthreads();

  // ---- tile 0 epilogue: accumulate only, NO atomics ----
  epilogue_tile<false>(acc, rc, rs, 0, row0, b, w, lane16, quad, l,
                       bq, bk, bv, ctx, ksum, qws, s_acc, c_acc);

  // ---- tile 1 GEMM + final epilogue (single per-block atomic set, issued early) ----
  gemm_tile(xh[1], xl[1], WTh, WTl, wbase, lane16, quad, acc);
  epilogue_tile<true>(acc, rc, rs, 64, row0 + 64, b, w, lane16, quad, l,
                      bq, bk, bv, ctx, ksum, qws, s_acc, c_acc);
}

// ---------------- kernel 2: out = (z .* q') @ (ctx_b @ Wo) + bo, column-split ----------------
// 1024 blocks x 512 thr (8 waves); block = 128 rows x 64 cols (ch = bid&1 selects the
// column half). Half-M (16+16KB) + ctxS 8KB = LDS 40960B EXACTLY -> 4 blocks/CU;
// grid = 4/CU x 256 CU = one balanced round. bo read from global (L2-hot, 512B).
__global__ __launch_bounds__(512) void k_zout(
    const unsigned short* __restrict__ qws,
    const float* __restrict__ Wo, const float* __restrict__ ctx,
    const float* __restrict__ bo, const float* __restrict__ ksum,
    float* __restrict__ out) {
  __shared__ __align__(16) unsigned char SM[40960];
  unsigned short* mh = (unsigned short*)SM;            // 8192 shorts (16KB)
  unsigned short* ml = (unsigned short*)(SM + 16384);  // 16KB
  float* ctxS = (float*)(SM + 32768);                  // 2048 f (8KB)
  const int tid = threadIdx.x;
  const int row0 = (blockIdx.x >> 1) * 128;
  const int ch = blockIdx.x & 1;                       // column half
  const int b = row0 >> 13;
  const int l = tid & 63, w = tid >> 6;
  const int lane16 = l & 15, quad = l >> 4;

  {  // async-stage ctx_b (8KB): wave w copies chunk w*1KB
    const char* gc = (const char*)(ctx + (size_t)b * 2048);
    int off = w * 1024 + l * 16;
    async16(gc + off, (char*)ctxS + off);
  }

  // A-frags (full K): q' from ws (frag-layout), z in-reg, scale+split — overlapped
  // with staging. Duplicated across the 2 col-halves (the price of 4 blocks/CU).
  short8 ah[4], al[4];
  {
    int trow = row0 + w * 16 + lane16;      // lane16 = t within the wave's 16-row strip
    const float* kg = ksum + b * 128;
#pragma unroll
    for (int ks = 0; ks < 4; ++ks) {
      union { short8 s8; unsigned short u[8]; } qq;
      qq.s8 = *(const short8*)&qws[(size_t)trow * 128 + ks * 32 + quad * 8];
      int kb = ks * 32 + quad * 8;
      float4 kf0 = *(const float4*)(kg + kb);
      float4 kf1 = *(const float4*)(kg + kb + 4);
      float kf[8] = {kf0.x, kf0.y, kf0.z, kf0.w, kf1.x, kf1.y, kf1.z, kf1.w};
      float s = 0.f;
#pragma unroll
      for (int j = 0; j < 8; ++j) s += bfdec(qq.u[j]) * kf[j];
      s += __shfl_xor(s, 16);        // combine the two 8-halves of the head
      float z = 1.0f / (s + 1e-6f);
      union { short8 s8; unsigned short u[8]; } H, L;
#pragma unroll
      for (int j = 0; j < 8; ++j) splitf(bfdec(qq.u[j]) * z, H.u[j], L.u[j]);
      ah[ks] = H.s8;
      al[ks] = L.s8;
    }
  }
  __syncthreads();                 // ctx_b staged (A-frag prologue hidden under it)

  // build half-M = ctx_b @ Wo[:, ch*64 .. +64) into mh/ml (frag-major permuted;
  // e-loop order identical to before -> M values bit-identical)
#pragma unroll
  for (int pp = 0; pp < 2; ++pp) {
    int p = pp * 512 + tid;        // 1024 (ocl,qcg) pairs
    int ocl = p & 63, qcg = p >> 6;
    int oc = ch * 64 + ocl;
    int h = qcg >> 1, d0 = (qcg & 1) * 8;
    const float* C = ctxS + h * 256;   // [d][e]
    float m[8] = {0.f, 0.f, 0.f, 0.f, 0.f, 0.f, 0.f, 0.f};
#pragma unroll 4
    for (int e = 0; e < 16; ++e) {
      float wv = Wo[(size_t)(h * 16 + e) * 128 + oc];
#pragma unroll
      for (int i = 0; i < 8; ++i) m[i] += C[(d0 + i) * 16 + e] * wv;
    }
    union { uint4 q; unsigned short u[8]; } oh, ol;
#pragma unroll
    for (int i = 0; i < 8; ++i) splitf(m[i], oh.u[i], ol.u[i]);
    int grp = (((ocl >> 4) * 4 + (qcg >> 2)) * 64) + (qcg & 3) * 16 + (ocl & 15);
    *(uint4*)&mh[grp * 8] = oh.q;
    *(uint4*)&ml[grp * 8] = ol.q;
  }
  __syncthreads();                 // half-M ready in LDS

  floatx4 oacc[4];
#pragma unroll
  for (int i = 0; i < 4; ++i) oacc[i] = (floatx4){0.f, 0.f, 0.f, 0.f};

#pragma unroll
  for (int nt = 0; nt < 4; ++nt) {
#pragma unroll
    for (int ks = 0; ks < 4; ++ks) {
      int moff = ((nt * 4 + ks) * 64 + l) * 8;        // frag-major: lane-contiguous 16B
      short8 wbh = *(const short8*)&mh[moff];
      short8 wbl = *(const short8*)&ml[moff];
      oacc[nt] = MFMA(ah[ks], wbh, oacc[nt], 0, 0, 0);
      oacc[nt] = MFMA(al[ks], wbh, oacc[nt], 0, 0, 0);
      oacc[nt] = MFMA(ah[ks], wbl, oacc[nt], 0, 0, 0);
    }
  }

#pragma unroll
  for (int nt = 0; nt < 4; ++nt) {
    int oc = ch * 64 + nt * 16 + lane16;
    float bb = bo[oc];             // L2-broadcast, replaces boS (saves 512B LDS -> 40KB exact)
#pragma unroll
    for (int r = 0; r < 4; ++r) {
      int t = row0 + w * 16 + quad * 4 + r;
      out[(size_t)t * 128 + oc] = oacc[nt][r] + bb;
    }
  }
}

extern "C" void kernel_launch(void* const* d_in, const int* in_sizes, int n_in,
                              void* d_out, int out_size, void* d_ws, size_t ws_size,
                              hipStream_t stream) {
  const float* x  = (const float*)d_in[0];
  const float* Wq = (const float*)d_in[1];
  const float* bq = (const float*)d_in[2];
  const float* Wk = (const float*)d_in[3];
  const float* bk = (const float*)d_in[4];
  const float* Wv = (const float*)d_in[5];
  const float* bv = (const float*)d_in[6];
  const float* Wo = (const float*)d_in[7];
  const float* bo = (const float*)d_in[8];
  float* out = (float*)d_out;

  // ws: qws 16.78MB | WTh 96KB | WTl 96KB | ctx 64KB | ksum 4KB | RC 256KB | RS 256KB
  unsigned short* qws = (unsigned short*)d_ws;         // 65536*128 shorts
  unsigned short* WTh = qws + 8388608;                 // 3 x 16384
  unsigned short* WTl = WTh + 49152;
  float* ctx  = (float*)(WTl + 49152);                 // 16384 f
  float* ksum = ctx + 16384;                           // 1024 f
  float* RC = ksum + 1024;                             // 65536 f
  float* RS = RC + 65536;                              // 65536 f

  k_prep<<<348, 256, 0, stream>>>(Wq, Wk, Wv, WTh, WTl, ctx, RC, RS);
  k_qkv<<<512, 512, 0, stream>>>(x, WTh, WTl, bq, bk, bv, RC, RS, ctx, ksum, qws);
  k_zout<<<1024, 512, 0, stream>>>(qws, Wo, ctx, bo, ksum, out);
}